// Round 3
// baseline (18.643 us; speedup 1.0000x reference)
//
#include <hip/hip_runtime.h>

// RBFLayer: B=4, N=16384, D=16, K=64
//   s  = scaling[0,0,:,0]            (D,)
//   Hx = x * s                       (B,N,D)
//   O[b,n,k] = sum_d (x[b,n,d]*s[d] - s[d]*centers[k,d])^2
// Outputs concatenated: O (B*N*K floats) then Hx (B*N*D floats).
//
// No LDS, no barrier: lane k holds scaled center row k in 16 VGPRs; each
// wave processes 8 rows via same-address float4 broadcast loads of x.

constexpr int D = 16;
constexpr int K = 64;
constexpr int ROWS_PER_BLOCK = 32;
constexpr int BLOCK = 256;

__global__ __launch_bounds__(BLOCK) void rbf_kernel(
    const float* __restrict__ x,        // (rows, D)
    const float* __restrict__ centers,  // (K, D)
    const float* __restrict__ scaling,  // (D,)
    float* __restrict__ O,              // (rows, K)
    float* __restrict__ Hx,             // (rows, D)
    int nRows)
{
    const int tid  = threadIdx.x;
    const int lane = tid & 63;          // = center index k
    const int rgrp = tid >> 6;          // 0..3 row-group within block

    const int blockRow0 = blockIdx.x * ROWS_PER_BLOCK;

    // ---- Independent Hx stream: 512 floats, float2/thread, coalesced. ----
    {
        const float2* xsrc = reinterpret_cast<const float2*>(x + (size_t)blockRow0 * D);
        const float2* s2p  = reinterpret_cast<const float2*>(scaling);
        float2 v  = xsrc[tid];
        float2 s2 = s2p[tid & 7];
        float2 h;
        h.x = v.x * s2.x;
        h.y = v.y * s2.y;
        reinterpret_cast<float2*>(Hx + (size_t)blockRow0 * D)[tid] = h;
    }

    // ---- s and scaled centers in registers. ----
    const float4* s4p = reinterpret_cast<const float4*>(scaling);
    float4 sv[4];
    #pragma unroll
    for (int q = 0; q < 4; ++q) sv[q] = s4p[q];

    float cs[D];
    {
        const float4* c4 = reinterpret_cast<const float4*>(centers + lane * D);
        #pragma unroll
        for (int q = 0; q < 4; ++q) {
            float4 cv = c4[q];
            cs[4 * q + 0] = cv.x * sv[q].x;
            cs[4 * q + 1] = cv.y * sv[q].y;
            cs[4 * q + 2] = cv.z * sv[q].z;
            cs[4 * q + 3] = cv.w * sv[q].w;
        }
    }

    // ---- 8 rows per wave; x row read via same-address broadcast loads. ----
    #pragma unroll
    for (int r = 0; r < ROWS_PER_BLOCK / 4; ++r) {
        const int row = blockRow0 + r * 4 + rgrp;
        if (row >= nRows) break;

        const float4* xr = reinterpret_cast<const float4*>(x + (size_t)row * D);
        float4 h0 = xr[0];
        float4 h1 = xr[1];
        float4 h2 = xr[2];
        float4 h3 = xr[3];

        float acc = 0.f;
        float d0;
        d0 = fmaf(h0.x, sv[0].x, -cs[0]);  acc = fmaf(d0, d0, acc);
        d0 = fmaf(h0.y, sv[0].y, -cs[1]);  acc = fmaf(d0, d0, acc);
        d0 = fmaf(h0.z, sv[0].z, -cs[2]);  acc = fmaf(d0, d0, acc);
        d0 = fmaf(h0.w, sv[0].w, -cs[3]);  acc = fmaf(d0, d0, acc);
        d0 = fmaf(h1.x, sv[1].x, -cs[4]);  acc = fmaf(d0, d0, acc);
        d0 = fmaf(h1.y, sv[1].y, -cs[5]);  acc = fmaf(d0, d0, acc);
        d0 = fmaf(h1.z, sv[1].z, -cs[6]);  acc = fmaf(d0, d0, acc);
        d0 = fmaf(h1.w, sv[1].w, -cs[7]);  acc = fmaf(d0, d0, acc);
        d0 = fmaf(h2.x, sv[2].x, -cs[8]);  acc = fmaf(d0, d0, acc);
        d0 = fmaf(h2.y, sv[2].y, -cs[9]);  acc = fmaf(d0, d0, acc);
        d0 = fmaf(h2.z, sv[2].z, -cs[10]); acc = fmaf(d0, d0, acc);
        d0 = fmaf(h2.w, sv[2].w, -cs[11]); acc = fmaf(d0, d0, acc);
        d0 = fmaf(h3.x, sv[3].x, -cs[12]); acc = fmaf(d0, d0, acc);
        d0 = fmaf(h3.y, sv[3].y, -cs[13]); acc = fmaf(d0, d0, acc);
        d0 = fmaf(h3.z, sv[3].z, -cs[14]); acc = fmaf(d0, d0, acc);
        d0 = fmaf(h3.w, sv[3].w, -cs[15]); acc = fmaf(d0, d0, acc);

        O[(size_t)row * K + lane] = acc;   // 256B contiguous per wave
    }
}

extern "C" void kernel_launch(void* const* d_in, const int* in_sizes, int n_in,
                              void* d_out, int out_size, void* d_ws, size_t ws_size,
                              hipStream_t stream) {
    const float* x       = (const float*)d_in[0];
    const float* centers = (const float*)d_in[1];
    const float* scaling = (const float*)d_in[2];

    const int nRows = in_sizes[0] / D;          // B*N = 65536
    float* O  = (float*)d_out;                  // nRows*K floats
    float* Hx = (float*)d_out + (size_t)nRows * K;

    const int grid = (nRows + ROWS_PER_BLOCK - 1) / ROWS_PER_BLOCK;  // 2048
    rbf_kernel<<<grid, BLOCK, 0, stream>>>(x, centers, scaling, O, Hx, nRows);
}